// Round 12
// baseline (45.525 us; speedup 1.0000x reference)
//
#include <hip/hip_runtime.h>
#include <math.h>

#define LOG2E 1.4426950408889634f
#define NW 16                 // waves per block
#define MAGIC 0x7F3A9C51u     // producer-done flag value (never 0xAAAAAAAA)

typedef short short8 __attribute__((ext_vector_type(8)));
typedef float f32x4  __attribute__((ext_vector_type(4)));

__device__ inline unsigned short f2bf(float f) {   // f32 -> bf16 bits, RNE
    unsigned int u = __float_as_uint(f);
    return (unsigned short)((u + 0x7FFFu + ((u >> 16) & 1u)) >> 16);
}

__device__ inline unsigned int cvtpk_bf16(float lo, float hi) {
    unsigned int r;
    asm("v_cvt_pk_bf16_f32 %0, %1, %2" : "=v"(r) : "v"(lo), "v"(hi));
    return r;   // low16 = bf16(lo), high16 = bf16(hi)
}

// ONE dispatch, fused R10: phase 1 packs the train B-fragment image into ws
// (each block packs its 1/grid share; all cross-block traffic is device-scope
// RMW atomics -> coherence point, no fence subtleties), per-wave flag poll,
// phase 2 = R10 main loop reading the packed image straight from L2.
// Image per point (64B): g0 dims0-7 | g1 dims8-15 | g2 dims0-6+n0@7 |
// g3 dims8-14+n1@7, n0+n1 = -(0.5*log2e)*||y||^2. No bulk LDS -> 2 blocks/CU.
__global__ __launch_bounds__(1024, 8) void kde_fused(
    const float* __restrict__ testX, const float* __restrict__ trainX,
    unsigned int* __restrict__ pkw,     // packed image, u32[nPad*16]
    unsigned int* __restrict__ flags,   // one flag per block, 64B stride
    float* __restrict__ out, int nTest, int nTrain, int nPad, int tpw, float Z)
{
    const int tid  = threadIdx.x;
    const int lane = tid & 63;
    const int w    = tid >> 6;            // wave 0..15
    const int g    = lane >> 4;
    const int l4   = lane & 15;
    const int h    = g & 1;
    const int rowBase = blockIdx.x * 16;
    const int grid = gridDim.x;
    const int ppb  = (nPad + grid - 1) / grid;   // points packed per block

    __shared__ float red[NW][16];

    // ---- Phase 1: pack this block's share. Worker i = (pt, half). ----
    for (int i = tid; i < ppb * 2; i += blockDim.x) {
        int pt = blockIdx.x * ppb + (i >> 1);
        int hf = i & 1;
        if (pt < nPad) {
            int ci = min(pt, nTrain - 1);
            const float4* p = (const float4*)(trainX + (size_t)ci * 16) + hf * 2;
            float4 qa = p[0], qb = p[1];
            float inv = (pt < nTrain) ? 0.0f : 2e30f;
            float pn = (qa.x*qa.x + qa.y*qa.y) + (qa.z*qa.z + qa.w*qa.w)
                     + (qb.x*qb.x + qb.y*qb.y) + (qb.z*qb.z + qb.w*qb.w) + inv;
            float n  = -(0.5f * LOG2E) * pn;
            unsigned int u0 = cvtpk_bf16(qa.x, qa.y);
            unsigned int u1 = cvtpk_bf16(qa.z, qa.w);
            unsigned int u2 = cvtpk_bf16(qb.x, qb.y);
            unsigned int u3 = cvtpk_bf16(qb.z, qb.w);
            unsigned int u3n = cvtpk_bf16(qb.z, n);
            // variant g at u32 offset ((pt>>4)*64 + (pt&15)*4 + g)*4
            unsigned int* q = pkw + ((size_t)(pt >> 4) * 64 + (pt & 15) * 4 + hf) * 4;
            atomicExch(&q[0], u0); atomicExch(&q[1], u1);
            atomicExch(&q[2], u2); atomicExch(&q[3], u3);
            unsigned int* q2 = q + 8;          // variant hf+2 (norm in slot 7)
            atomicExch(&q2[0], u0); atomicExch(&q2[1], u1);
            atomicExch(&q2[2], u2); atomicExch(&q2[3], u3n);
        }
    }

    // ---- A fragment while pack stores fly: rows rowBase..+15 ----
    const int m = min(rowBase + l4, nTest - 1);
    const float4* xp = (const float4*)(testX + (size_t)m * 16);
    float4 x0 = xp[0], x1 = xp[1], x2 = xp[2], x3 = xp[3];
    float xs[16] = {x0.x,x0.y,x0.z,x0.w, x1.x,x1.y,x1.z,x1.w,
                    x2.x,x2.y,x2.z,x2.w, x3.x,x3.y,x3.z,x3.w};
    #pragma unroll
    for (int i = 0; i < 16; ++i) xs[i] *= LOG2E;
    float xn = 0.0f;
    #pragma unroll
    for (int i = 0; i < 16; ++i) xn = fmaf(xs[i], xs[i], xn);
    xn *= 0.5f / LOG2E;                   // 0.5*log2e*||x||^2 of row rowBase+l4

    short8 afrag;
    #pragma unroll
    for (int i = 0; i < 8; ++i) {
        float fx = xs[h * 8 + i];
        unsigned short hb = f2bf(fx);
        float hf2 = __uint_as_float((unsigned int)hb << 16);
        unsigned short lb = f2bf(fx - hf2);
        afrag[i] = (short)((g < 2) ? hb : lb);   // k<16: hi, k>=16: lo
    }
    if (g >= 2) afrag[7] = (short)0x3F80;        // bf16(1.0) at k=23 / k=31

    f32x4 nxv;                                    // invariant MFMA C operand
    #pragma unroll
    for (int r = 0; r < 4; ++r)
        nxv[r] = -__shfl(xn, (lane & 48) + g * 4 + r);

    // ---- signal: this block's share is globally visible ----
    __syncthreads();                               // drains vmcnt (all RMWs acked)
    if (tid == 0) atomicExch(&flags[blockIdx.x * 16], MAGIC);

    // ---- per-wave poll for the producers of this wave's slice ----
    const int sliceBeg = w * tpw * 16;
    int pb0 = sliceBeg / ppb;
    int pbN = (sliceBeg + tpw * 16 - 1) / ppb;
    if (pbN >= grid) pbN = grid - 1;
    for (;;) {
        unsigned int v = MAGIC;
        int idx = pb0 + lane;
        if (idx <= pbN) v = atomicOr(&flags[idx * 16], 0u);   // RMW read
        if (__all(v == MAGIC)) break;
        __builtin_amdgcn_s_sleep(32);
    }
    __builtin_amdgcn_fence(__ATOMIC_ACQUIRE, "agent");

    // ---- Phase 2 (R10 main): wave reads its slice of the packed image ----
    const short8* pk = (const short8*)pkw + (size_t)w * tpw * 64 + (l4 * 4 + g);

    float rsA[4] = {0,0,0,0}, rsB[4] = {0,0,0,0};
    for (int t = 0; t < tpw; t += 4) {
        short8 b0 = pk[(size_t)(t+0) * 64];
        short8 b1 = pk[(size_t)(t+1) * 64];
        short8 b2 = pk[(size_t)(t+2) * 64];
        short8 b3 = pk[(size_t)(t+3) * 64];
        f32x4 c0 = __builtin_amdgcn_mfma_f32_16x16x32_bf16(afrag, b0, nxv, 0,0,0);
        f32x4 c1 = __builtin_amdgcn_mfma_f32_16x16x32_bf16(afrag, b1, nxv, 0,0,0);
        f32x4 c2 = __builtin_amdgcn_mfma_f32_16x16x32_bf16(afrag, b2, nxv, 0,0,0);
        f32x4 c3 = __builtin_amdgcn_mfma_f32_16x16x32_bf16(afrag, b3, nxv, 0,0,0);
        #pragma unroll
        for (int r = 0; r < 4; ++r) {
            rsA[r] += __builtin_amdgcn_exp2f(c0[r]);
            rsB[r] += __builtin_amdgcn_exp2f(c1[r]);
            rsA[r] += __builtin_amdgcn_exp2f(c2[r]);
            rsB[r] += __builtin_amdgcn_exp2f(c3[r]);
        }
    }

    // Reduce across the 16 columns (low-4 lane bits).
    float rs0 = rsA[0] + rsB[0], rs1 = rsA[1] + rsB[1];
    float rs2 = rsA[2] + rsB[2], rs3 = rsA[3] + rsB[3];
    #pragma unroll
    for (int off = 1; off <= 8; off <<= 1) {
        rs0 += __shfl_xor(rs0, off);
        rs1 += __shfl_xor(rs1, off);
        rs2 += __shfl_xor(rs2, off);
        rs3 += __shfl_xor(rs3, off);
    }
    if (l4 == 0) {
        red[w][g * 4 + 0] = rs0;
        red[w][g * 4 + 1] = rs1;
        red[w][g * 4 + 2] = rs2;
        red[w][g * 4 + 3] = rs3;
    }
    __syncthreads();

    if (tid < 16) {
        float s = 0.0f;
        #pragma unroll
        for (int k = 0; k < NW; ++k) s += red[k][tid];
        const int row = rowBase + tid;
        if (row < nTest) out[row] = __logf(s) - Z;
    }
}

extern "C" void kernel_launch(void* const* d_in, const int* in_sizes, int n_in,
                              void* d_out, int out_size, void* d_ws, size_t ws_size,
                              hipStream_t stream) {
    const float* testX  = (const float*)d_in[0];
    const float* trainX = (const float*)d_in[1];
    float* out = (float*)d_out;

    const int D = 16;
    const int nTest  = in_sizes[0] / D;   // 4096
    const int nTrain = in_sizes[1] / D;   // 8192

    const float Z = 0.5f * (float)D * logf(2.0f * (float)M_PI) + logf((float)nTrain);

    // tiles per wave (multiple of 4), padded point count.
    int tiles = (nTrain + 15) / 16;
    int tpw   = (tiles + NW - 1) / NW;
    tpw = (tpw + 3) & ~3;
    int nPad = NW * tpw * 16;             // 8192 at bench size

    // ws layout: packed image (nPad*64B) | flags (grid * 64B)
    unsigned int* pkw   = (unsigned int*)d_ws;
    unsigned int* flags = (unsigned int*)((char*)d_ws + (size_t)nPad * 64);

    const int grid = (nTest + 15) / 16;   // 256 blocks, 16 rows each
    kde_fused<<<grid, 1024, 0, stream>>>(testX, trainX, pkw, flags, out,
                                         nTest, nTrain, nPad, tpw, Z);
}

// Round 13
// 22.337 us; speedup vs baseline: 2.0381x; 2.0381x over previous
//
#include <hip/hip_runtime.h>
#include <math.h>

#define LOG2E 1.4426950408889634f
#define NW 16   // waves per block

typedef short short8 __attribute__((ext_vector_type(8)));
typedef float f32x4  __attribute__((ext_vector_type(4)));

__device__ inline unsigned short f2bf(float f) {   // f32 -> bf16 bits, RNE
    unsigned int u = __float_as_uint(f);
    return (unsigned short)((u + 0x7FFFu + ((u >> 16) & 1u)) >> 16);
}

__device__ inline unsigned int cvtpk_bf16(float lo, float hi) {
    unsigned int r;
    asm("v_cvt_pk_bf16_f32 %0, %1, %2" : "=v"(r) : "v"(lo), "v"(hi));
    return r;   // low16 = bf16(lo), high16 = bf16(hi)
}

// ONE dispatch, ZERO staging. 256 blocks x 1024 threads (16 waves,
// 1 block/CU). Block owns 16 test rows; waves partition train (512 pts).
// Key: the slot-7 norm trick splits ||y||^2 by halves (n0 at k=23, n1 at
// k=31), and lane-group g2 needs only n0 = f(dims 0-7) = f(its OWN 32B),
// g3 only n1. So every lane builds its full B-fragment from its own
// 2 x dwordx4 global load: 8-FMA half-norm, 4 cvt_pk (slot7 <- norm via
// 1 cndmask for g>=2), 1 MFMA (invariant C = -testnorm rows), 4 exp2.
// No LDS in the loop, no shuffles, no cross-lane anything. Lanes g0/g2
// (g1/g3) read identical addresses -> coalescer dedupes -> 512KB/block L2.
__global__ __launch_bounds__(1024, 4) void kde_fused(
    const float* __restrict__ testX, const float* __restrict__ trainX,
    float* __restrict__ out, int nTest, int nTrain, float Z)
{
    const int tid  = threadIdx.x;
    const int lane = tid & 63;
    const int w    = tid >> 6;            // wave 0..15
    const int g    = lane >> 4;
    const int l4   = lane & 15;
    const int h    = g & 1;               // which 8-dim half this lane holds
    const bool lo  = (g >= 2);            // lo-compensation lane groups
    const int rowBase = blockIdx.x * 16;

    __shared__ float red[NW][16];

    // ---- A fragment: rows rowBase..+15, [x_hi | x_lo], slots 23/31 = 1.0 ----
    const int m = min(rowBase + l4, nTest - 1);
    const float4* xp = (const float4*)(testX + (size_t)m * 16);
    float4 x0 = xp[0], x1 = xp[1], x2 = xp[2], x3 = xp[3];
    x0.x *= LOG2E; x0.y *= LOG2E; x0.z *= LOG2E; x0.w *= LOG2E;
    x1.x *= LOG2E; x1.y *= LOG2E; x1.z *= LOG2E; x1.w *= LOG2E;
    x2.x *= LOG2E; x2.y *= LOG2E; x2.z *= LOG2E; x2.w *= LOG2E;
    x3.x *= LOG2E; x3.y *= LOG2E; x3.z *= LOG2E; x3.w *= LOG2E;
    float xn = ((x0.x*x0.x + x0.y*x0.y) + (x0.z*x0.z + x0.w*x0.w))
             + ((x1.x*x1.x + x1.y*x1.y) + (x1.z*x1.z + x1.w*x1.w))
             + ((x2.x*x2.x + x2.y*x2.y) + (x2.z*x2.z + x2.w*x2.w))
             + ((x3.x*x3.x + x3.y*x3.y) + (x3.z*x3.z + x3.w*x3.w));
    xn *= 0.5f / LOG2E;                   // 0.5*log2e*||x||^2 of row rowBase+l4

    float fx[8];                          // this lane's half (constant-indexed)
    fx[0] = h ? x2.x : x0.x;  fx[1] = h ? x2.y : x0.y;
    fx[2] = h ? x2.z : x0.z;  fx[3] = h ? x2.w : x0.w;
    fx[4] = h ? x3.x : x1.x;  fx[5] = h ? x3.y : x1.y;
    fx[6] = h ? x3.z : x1.z;  fx[7] = h ? x3.w : x1.w;

    short8 afrag;
    #pragma unroll
    for (int i = 0; i < 8; ++i) {
        float v = fx[i];
        unsigned short hb = f2bf(v);
        float hf = __uint_as_float((unsigned int)hb << 16);
        unsigned short lb = f2bf(v - hf);
        afrag[i] = (short)(lo ? lb : hb);  // k<16: hi, k>=16: lo
    }
    if (lo) afrag[7] = (short)0x3F80;      // bf16(1.0) at k=23 / k=31

    f32x4 nxv;                             // invariant MFMA C operand
    #pragma unroll
    for (int r = 0; r < 4; ++r)
        nxv[r] = -__shfl(xn, (lane & 48) + g * 4 + r);

    // ---- wave's train slice ----
    const int perWave = ((nTrain + NW * 16 - 1) / (NW * 16)) * 16;
    const int nt   = perWave >> 4;
    const int tb   = w * perWave;
    const int nMax = nTrain - 1;
    const float NSC = -0.5f * LOG2E;

    float rsA[4] = {0,0,0,0}, rsB[4] = {0,0,0,0};

    #define LOADT(T, QA, QB)                                                  \
        {   int pt = tb + (T) * 16 + l4;                                      \
            const float4* p =                                                 \
                (const float4*)(trainX + (size_t)min(pt, nMax) * 16) + h * 2; \
            QA = p[0]; QB = p[1]; }

    #define PROC(T, QA, QB, RS)                                               \
        {   float pn = ((QA.x*QA.x + QA.y*QA.y) + (QA.z*QA.z + QA.w*QA.w))    \
                     + ((QB.x*QB.x + QB.y*QB.y) + (QB.z*QB.z + QB.w*QB.w));   \
            pn = (tb + (T) * 16 + l4 <= nMax) ? pn : 1e30f;                   \
            float nv  = pn * NSC;                                             \
            float hi7 = lo ? nv : QB.w;                                       \
            union { unsigned int u[4]; short8 s; } bb;                        \
            bb.u[0] = cvtpk_bf16(QA.x, QA.y);                                 \
            bb.u[1] = cvtpk_bf16(QA.z, QA.w);                                 \
            bb.u[2] = cvtpk_bf16(QB.x, QB.y);                                 \
            bb.u[3] = cvtpk_bf16(QB.z, hi7);                                  \
            f32x4 c = __builtin_amdgcn_mfma_f32_16x16x32_bf16(                \
                          afrag, bb.s, nxv, 0, 0, 0);                         \
            RS[0] += __builtin_amdgcn_exp2f(c[0]);                            \
            RS[1] += __builtin_amdgcn_exp2f(c[1]);                            \
            RS[2] += __builtin_amdgcn_exp2f(c[2]);                            \
            RS[3] += __builtin_amdgcn_exp2f(c[3]); }

    const int nt4 = nt & ~3;
    for (int t = 0; t < nt4; t += 4) {
        float4 a0,b0,a1,b1,a2,b2,a3,b3;
        LOADT(t+0,a0,b0); LOADT(t+1,a1,b1);
        LOADT(t+2,a2,b2); LOADT(t+3,a3,b3);
        PROC(t+0,a0,b0,rsA); PROC(t+1,a1,b1,rsB);
        PROC(t+2,a2,b2,rsA); PROC(t+3,a3,b3,rsB);
    }
    for (int t = nt4; t < nt; ++t) {      // tail (unused at bench sizes)
        float4 ta,tbv;
        LOADT(t,ta,tbv);
        PROC(t,ta,tbv,rsA);
    }
    #undef LOADT
    #undef PROC

    // Reduce across the 16 columns (low-4 lane bits).
    float rs0 = rsA[0] + rsB[0], rs1 = rsA[1] + rsB[1];
    float rs2 = rsA[2] + rsB[2], rs3 = rsA[3] + rsB[3];
    #pragma unroll
    for (int off = 1; off <= 8; off <<= 1) {
        rs0 += __shfl_xor(rs0, off);
        rs1 += __shfl_xor(rs1, off);
        rs2 += __shfl_xor(rs2, off);
        rs3 += __shfl_xor(rs3, off);
    }
    if (l4 == 0) {
        red[w][g * 4 + 0] = rs0;
        red[w][g * 4 + 1] = rs1;
        red[w][g * 4 + 2] = rs2;
        red[w][g * 4 + 3] = rs3;
    }
    __syncthreads();

    if (tid < 16) {
        float s = 0.0f;
        #pragma unroll
        for (int k = 0; k < NW; ++k) s += red[k][tid];
        const int row = rowBase + tid;
        if (row < nTest) out[row] = __logf(s) - Z;
    }
}

extern "C" void kernel_launch(void* const* d_in, const int* in_sizes, int n_in,
                              void* d_out, int out_size, void* d_ws, size_t ws_size,
                              hipStream_t stream) {
    const float* testX  = (const float*)d_in[0];
    const float* trainX = (const float*)d_in[1];
    float* out = (float*)d_out;

    const int D = 16;
    const int nTest  = in_sizes[0] / D;   // 4096
    const int nTrain = in_sizes[1] / D;   // 8192

    const float Z = 0.5f * (float)D * logf(2.0f * (float)M_PI) + logf((float)nTrain);

    const int grid = (nTest + 15) / 16;   // 256 blocks, 16 rows each
    kde_fused<<<grid, 1024, 0, stream>>>(testX, trainX, out, nTest, nTrain, Z);
}